// Round 15
// baseline (238.972 us; speedup 1.0000x reference)
//
#include <hip/hip_runtime.h>
#include <hip/hip_cooperative_groups.h>

namespace cg = cooperative_groups;

// ScaledDotProductAttention B=8, L=2048, D=64, fp32 in/out.
//
// SINGLE cooperative kernel (ws >= 8 MB): phase 1 = fragment-major prepass
// (R13's verified ~7us win: kills the row-per-lane VMEM scatter), grid.sync,
// phase 2 = R14's attn_tlp body VERBATIM (4 waves/SIMD, zero-LDS hot loop).
//
// XCD-local handoff: block (b,qbi) = blockIdx (qbi*8+b) prepares K/V frags of
// tile kt=qbi, batch b. blockIdx%8 == b for every block of batch b, so under
// the round-robin XCD heuristic each batch's full 512 KB frag set is written
// AND read on one XCD -> phase-2 reads are warm local-L2 hits, and the
// prepass launch + inter-kernel gap disappear.
//
// Fragment layouts (R13-verified):
//   K16F[((b*64+kt)*4 + s*2+c)*512 + lane*8]  (half8 = bk[s][c] of tile kt)
//   VT16F[((b*64+kt)*8 + d*2+ks)*256 + lane*4] (half4 = av[d][ks])
//
// Fallback 1 (cooperative launch rejected): R14 two-launch path (verbatim).
// Fallback 2 (ws too small): proven R3 kernel.

#define B_ 8
#define L_ 2048
#define D_ 64
#define NT 256

typedef _Float16 half8_t __attribute__((ext_vector_type(8)));
typedef _Float16 half4_t __attribute__((ext_vector_type(4)));
typedef float f32x4 __attribute__((ext_vector_type(4)));

#define SCALE_LOG2E 0.1803368801111244f   // 0.125 * log2(e)

// Load K B-frags of tile KT: one fully-coalesced half8/lane stream per plane.
#define LOADK(KT, BK)                                                           \
    {                                                                           \
        _Pragma("unroll") for (int s = 0; s < 2; ++s)                           \
        _Pragma("unroll") for (int c = 0; c < 2; ++c)                           \
            BK[s][c] = *(const half8_t*)&KbF[((size_t)(KT) * 4 + s * 2 + c) * 512 + lane * 8]; \
    }

// Process tile KT using pre-loaded K frags BK.
#define PROC(KT, BK)                                                            \
    {                                                                           \
        half4_t av[4][2];                                                       \
        _Pragma("unroll") for (int d = 0; d < 4; ++d)                           \
        _Pragma("unroll") for (int ks = 0; ks < 2; ++ks)                        \
            av[d][ks] = *(const half4_t*)&VbF[((size_t)(KT) * 8 + d * 2 + ks) * 256 + lane * 4]; \
        f32x4 sc[2][2];                                                         \
        _Pragma("unroll") for (int ks = 0; ks < 2; ++ks)                        \
        _Pragma("unroll") for (int qs = 0; qs < 2; ++qs) {                      \
            f32x4 acc = (f32x4){0.f, 0.f, 0.f, 0.f};                            \
            acc = __builtin_amdgcn_mfma_f32_16x16x32_f16(BK[ks][0], bq[qs][0], acc, 0, 0, 0); \
            acc = __builtin_amdgcn_mfma_f32_16x16x32_f16(BK[ks][1], bq[qs][1], acc, 0, 0, 0); \
            sc[ks][qs] = acc;                                                   \
        }                                                                       \
        half4_t pb[2][2];                                                       \
        _Pragma("unroll") for (int ks = 0; ks < 2; ++ks)                        \
        _Pragma("unroll") for (int qs = 0; qs < 2; ++qs) {                      \
            const float p0 = __builtin_exp2f(sc[ks][qs][0]);                    \
            const float p1 = __builtin_exp2f(sc[ks][qs][1]);                    \
            const float p2 = __builtin_exp2f(sc[ks][qs][2]);                    \
            const float p3 = __builtin_exp2f(sc[ks][qs][3]);                    \
            lacc[qs] += (p0 + p1) + (p2 + p3);                                  \
            half4_t pv;                                                         \
            pv[0] = (_Float16)p0; pv[1] = (_Float16)p1;                         \
            pv[2] = (_Float16)p2; pv[3] = (_Float16)p3;                         \
            pb[ks][qs] = pv;                                                    \
        }                                                                       \
        _Pragma("unroll") for (int qs = 0; qs < 2; ++qs)                        \
        _Pragma("unroll") for (int d = 0; d < 4; ++d)                           \
        _Pragma("unroll") for (int ks = 0; ks < 2; ++ks)                        \
            ofr[qs][d] = __builtin_amdgcn_mfma_f32_16x16x16f16(av[d][ks], pb[ks][qs], ofr[qs][d], 0, 0, 0); \
    }

// The attention body shared by the cooperative and two-launch variants.
#define ATTN_BODY                                                               \
    const _Float16* KbF = K16F + (size_t)b * 64 * 4 * 512;                      \
    const _Float16* VbF = VT16F + (size_t)b * 64 * 8 * 256;                     \
    half8_t bq[2][2];                                                           \
    _Pragma("unroll") for (int qs = 0; qs < 2; ++qs) {                          \
        const float* qp = Q + ((size_t)b * L_ + qb + qs * 16 + l15) * D_ + quad * 8; \
        _Pragma("unroll") for (int c = 0; c < 2; ++c) {                         \
            const float4 f0 = *(const float4*)(qp + c * 32);                    \
            const float4 f1 = *(const float4*)(qp + c * 32 + 4);                \
            bq[qs][c][0] = (_Float16)(f0.x * SCALE_LOG2E);                      \
            bq[qs][c][1] = (_Float16)(f0.y * SCALE_LOG2E);                      \
            bq[qs][c][2] = (_Float16)(f0.z * SCALE_LOG2E);                      \
            bq[qs][c][3] = (_Float16)(f0.w * SCALE_LOG2E);                      \
            bq[qs][c][4] = (_Float16)(f1.x * SCALE_LOG2E);                      \
            bq[qs][c][5] = (_Float16)(f1.y * SCALE_LOG2E);                      \
            bq[qs][c][6] = (_Float16)(f1.z * SCALE_LOG2E);                      \
            bq[qs][c][7] = (_Float16)(f1.w * SCALE_LOG2E);                      \
        }                                                                       \
    }                                                                           \
    f32x4 ofr[2][4];                                                            \
    _Pragma("unroll") for (int qs = 0; qs < 2; ++qs)                            \
        _Pragma("unroll") for (int d = 0; d < 4; ++d)                           \
            ofr[qs][d] = (f32x4){0.f, 0.f, 0.f, 0.f};                           \
    float lacc[2] = {0.f, 0.f};                                                 \
    const int kt0 = wave * 8;                                                   \
    half8_t bkA[2][2], bkB[2][2];                                               \
    LOADK(kt0, bkA);                                                            \
    for (int it = 0; it < 4; ++it) {                                            \
        const int kta = kt0 + it * 2;                                           \
        LOADK(kta + 1, bkB);                                                    \
        PROC(kta, bkA);                                                         \
        LOADK(kta + 2, bkA);                                                    \
        PROC(kta + 1, bkB);                                                     \
    }                                                                           \
    _Pragma("unroll") for (int qs = 0; qs < 2; ++qs) {                          \
        float v = lacc[qs];                                                     \
        v += __shfl_xor(v, 16, 64);                                             \
        v += __shfl_xor(v, 32, 64);                                             \
        lacc[qs] = v;                                                           \
    }                                                                           \
    if (quad == 0) {                                                            \
        Lred[wave * 32 + l15] = lacc[0];                                        \
        Lred[wave * 32 + 16 + l15] = lacc[1];                                   \
    }                                                                           \
    _Pragma("unroll") for (int qs = 0; qs < 2; ++qs) {                          \
        __syncthreads();                                                        \
        _Pragma("unroll") for (int d = 0; d < 4; ++d)                           \
            _Pragma("unroll") for (int r = 0; r < 4; ++r)                       \
                Ored[(wave * 64 + lane) * 17 + d * 4 + r] = ofr[qs][d][r];      \
        __syncthreads();                                                        \
        if (wave < 4) {                                                         \
            float lt = 0.f;                                                     \
            _Pragma("unroll") for (int w2 = 0; w2 < 8; ++w2)                    \
                lt += Lred[w2 * 32 + qs * 16 + l15];                            \
            const float inv = 1.0f / lt;                                        \
            f32x4 osum = (f32x4){0.f, 0.f, 0.f, 0.f};                           \
            _Pragma("unroll") for (int w2 = 0; w2 < 8; ++w2) {                  \
                const float* src = &Ored[(w2 * 64 + lane) * 17 + wave * 4];     \
                osum[0] += src[0]; osum[1] += src[1];                           \
                osum[2] += src[2]; osum[3] += src[3];                           \
            }                                                                   \
            float4 outv;                                                        \
            outv.x = osum[0] * inv; outv.y = osum[1] * inv;                     \
            outv.z = osum[2] * inv; outv.w = osum[3] * inv;                     \
            *(float4*)&O[((size_t)b * L_ + qb + qs * 16 + l15) * D_ + wave * 16 + quad * 4] = outv; \
        }                                                                       \
    }

// ------------------------------------------------------ cooperative fused --
__global__ __launch_bounds__(512, 4) void attn_coop(
    const float* __restrict__ Q, const float* __restrict__ K,
    const float* __restrict__ V,
    _Float16* __restrict__ K16F, _Float16* __restrict__ VT16F,
    float* __restrict__ O)
{
    __shared__ float Ored[512 * 17];
    __shared__ float Lred[256];

    const int t    = threadIdx.x;
    const int wave = t >> 6;
    const int lane = t & 63;
    const int quad = lane >> 4;
    const int l15  = lane & 15;

    const int b   = blockIdx.x & 7;            // batch <-> XCD affinity
    const int qbi = blockIdx.x >> 3;           // 0..63
    const int qb  = qbi * 32;
    const int kt  = qbi;                       // this block also preps tile kt

    // ---- phase 1: build fragment-major K/V for tile (b, kt) ----
    if (wave < 4) {
        const int p = wave;                    // plane = s*2 + c
        const int s = p >> 1, c = p & 1;
        const int row = kt * 32 + s * 16 + l15;
        const float* kp = K + ((size_t)b * L_ + row) * D_ + c * 32 + quad * 8;
        const float4 f0 = *(const float4*)kp;
        const float4 f1 = *(const float4*)(kp + 4);
        half8_t w;
        w[0] = (_Float16)f0.x; w[1] = (_Float16)f0.y;
        w[2] = (_Float16)f0.z; w[3] = (_Float16)f0.w;
        w[4] = (_Float16)f1.x; w[5] = (_Float16)f1.y;
        w[6] = (_Float16)f1.z; w[7] = (_Float16)f1.w;
        *(half8_t*)&K16F[((size_t)(b * 64 + kt) * 4 + p) * 512 + lane * 8] = w;
    } else {
        #pragma unroll
        for (int j = 0; j < 2; ++j) {
            const int p = (wave - 4) * 2 + j;  // plane = d*2 + ks
            const int d = p >> 1, ks = p & 1;
            const int row = kt * 32 + ks * 16 + quad * 4;
            const int col = d * 16 + l15;
            const float* vp = V + ((size_t)b * L_ + row) * D_ + col;
            half4_t a;
            a[0] = (_Float16)vp[0];
            a[1] = (_Float16)vp[D_];
            a[2] = (_Float16)vp[2 * D_];
            a[3] = (_Float16)vp[3 * D_];
            *(half4_t*)&VT16F[((size_t)(b * 64 + kt) * 8 + p) * 256 + lane * 4] = a;
        }
    }

    __threadfence();               // make frag writes device-visible
    cg::this_grid().sync();        // all frags ready

    // ---- phase 2: R14 attn_tlp body (verbatim) ----
    ATTN_BODY
}

// ------------------------------------------------------------ prepass_frag --
// Fallback path (R14 verbatim). blocks 0..511: K frags; 512..1023: V frags.
__global__ __launch_bounds__(NT) void prepass_frag(
    const float* __restrict__ K, const float* __restrict__ V,
    _Float16* __restrict__ K16F, _Float16* __restrict__ VT16F)
{
    const int blk = blockIdx.x;
    const int t = threadIdx.x;
    if (blk < 512) {
        const int b  = blk >> 6;
        const int kt = blk & 63;
        const int p    = t >> 6;
        const int lane = t & 63;
        const int quad = lane >> 4;
        const int l15  = lane & 15;
        const int s = p >> 1, c = p & 1;
        const int row = kt * 32 + s * 16 + l15;
        const float* kp = K + ((size_t)b * L_ + row) * D_ + c * 32 + quad * 8;
        const float4 f0 = *(const float4*)kp;
        const float4 f1 = *(const float4*)(kp + 4);
        half8_t w;
        w[0] = (_Float16)f0.x; w[1] = (_Float16)f0.y;
        w[2] = (_Float16)f0.z; w[3] = (_Float16)f0.w;
        w[4] = (_Float16)f1.x; w[5] = (_Float16)f1.y;
        w[6] = (_Float16)f1.z; w[7] = (_Float16)f1.w;
        *(half8_t*)&K16F[((size_t)(b * 64 + kt) * 4 + p) * 512 + lane * 8] = w;
    } else {
        const int vb = blk - 512;
        const int b  = vb >> 6;
        const int kt = vb & 63;
        #pragma unroll
        for (int i = 0; i < 2; ++i) {
            const int slot = i * NT + t;
            const int p    = slot >> 6;
            const int lane = slot & 63;
            const int quad = lane >> 4;
            const int l15  = lane & 15;
            const int d = p >> 1, ks = p & 1;
            const int row = kt * 32 + ks * 16 + quad * 4;
            const int col = d * 16 + l15;
            const float* vp = V + ((size_t)b * L_ + row) * D_ + col;
            half4_t a;
            a[0] = (_Float16)vp[0];
            a[1] = (_Float16)vp[D_];
            a[2] = (_Float16)vp[2 * D_];
            a[3] = (_Float16)vp[3 * D_];
            *(half4_t*)&VT16F[((size_t)(b * 64 + kt) * 8 + p) * 256 + lane * 4] = a;
        }
    }
}

__global__ __launch_bounds__(512, 4) void attn_tlp(
    const float* __restrict__ Q,
    const _Float16* __restrict__ K16F,
    const _Float16* __restrict__ VT16F,
    float* __restrict__ O)
{
    __shared__ float Ored[512 * 17];
    __shared__ float Lred[256];

    const int t    = threadIdx.x;
    const int wave = t >> 6;
    const int lane = t & 63;
    const int quad = lane >> 4;
    const int l15  = lane & 15;

    const int b   = blockIdx.x & 7;
    const int qbi = blockIdx.x >> 3;
    const int qb  = qbi * 32;

    ATTN_BODY
}

// ------------------------------------------------- fallback (R3, no ws) --
#define KS 72
__global__ __launch_bounds__(NT) void attn_mfma_f16(
    const float* __restrict__ Q, const float* __restrict__ K,
    const float* __restrict__ V, float* __restrict__ O)
{
    __shared__ __align__(16) _Float16 Kt[64 * KS];
    __shared__ __align__(16) _Float16 Vt[D_ * KS];
    __shared__ __align__(16) _Float16 Pt[4][16 * KS];

    const int t = threadIdx.x;
    const int wave = t >> 6, lane = t & 63, quad = lane >> 4, l15 = lane & 15;
    const int bpb = L_ / 64;
    const int b = blockIdx.x / bpb;
    const int qb = (blockIdx.x % bpb) * 64 + wave * 16;
    const size_t boff = (size_t)b * L_ * D_;

    half8_t aq[2];
    {
        const float* qp = Q + boff + (size_t)(qb + l15) * D_ + quad * 8;
        #pragma unroll
        for (int c = 0; c < 2; ++c) {
            const float4* p4 = (const float4*)(qp + c * 32);
            const float4 f0 = p4[0], f1 = p4[1];
            aq[c][0] = (_Float16)f0.x; aq[c][1] = (_Float16)f0.y;
            aq[c][2] = (_Float16)f0.z; aq[c][3] = (_Float16)f0.w;
            aq[c][4] = (_Float16)f1.x; aq[c][5] = (_Float16)f1.y;
            aq[c][6] = (_Float16)f1.z; aq[c][7] = (_Float16)f1.w;
        }
    }
    f32x4 ofr[4];
    #pragma unroll
    for (int d = 0; d < 4; ++d) ofr[d] = (f32x4){0.f, 0.f, 0.f, 0.f};
    float lacc[4] = {0.f, 0.f, 0.f, 0.f};
    const int skey = t & 63, sdg = t >> 6;
    _Float16* Pw = &Pt[wave][0];

    for (int kt = 0; kt < L_ / 64; ++kt) {
        __syncthreads();
        {
            const float4* kg4 = (const float4*)(K + boff + (size_t)(kt * 64 + skey) * D_ + sdg * 16);
            const float4 f0 = kg4[0], f1 = kg4[1], f2 = kg4[2], f3 = kg4[3];
            half8_t w0, w1;
            w0[0] = (_Float16)f0.x; w0[1] = (_Float16)f0.y;
            w0[2] = (_Float16)f0.z; w0[3] = (_Float16)f0.w;
            w0[4] = (_Float16)f1.x; w0[5] = (_Float16)f1.y;
            w0[6] = (_Float16)f1.z; w0[7] = (_Float16)f1.w;
            w1[0] = (_Float16)f2.x; w1[1] = (_Float16)f2.y;
            w1[2] = (_Float16)f2.z; w1[3] = (_Float16)f2.w;
            w1[4] = (_Float16)f3.x; w1[5] = (_Float16)f3.y;
            w1[6] = (_Float16)f3.z; w1[7] = (_Float16)f3.w;
            *(half8_t*)&Kt[skey * KS + sdg * 16] = w0;
            *(half8_t*)&Kt[skey * KS + sdg * 16 + 8] = w1;
        }
        {
            const float4* vg4 = (const float4*)(V + boff + (size_t)(kt * 64 + skey) * D_ + sdg * 16);
            #pragma unroll
            for (int i = 0; i < 4; ++i) {
                const float4 f = vg4[i];
                const int d0 = sdg * 16 + i * 4;
                Vt[(d0 + 0) * KS + skey] = (_Float16)f.x;
                Vt[(d0 + 1) * KS + skey] = (_Float16)f.y;
                Vt[(d0 + 2) * KS + skey] = (_Float16)f.z;
                Vt[(d0 + 3) * KS + skey] = (_Float16)f.w;
            }
        }
        __syncthreads();
        #pragma unroll
        for (int s = 0; s < 4; ++s) {
            const half8_t bk0 = *(const half8_t*)&Kt[(s * 16 + l15) * KS + quad * 8];
            const half8_t bk1 = *(const half8_t*)&Kt[(s * 16 + l15) * KS + 32 + quad * 8];
            f32x4 sc = (f32x4){0.f, 0.f, 0.f, 0.f};
            sc = __builtin_amdgcn_mfma_f32_16x16x32_f16(aq[0], bk0, sc, 0, 0, 0);
            sc = __builtin_amdgcn_mfma_f32_16x16x32_f16(aq[1], bk1, sc, 0, 0, 0);
            #pragma unroll
            for (int r = 0; r < 4; ++r) {
                const float p = __expf(sc[r] * 0.125f);
                lacc[r] += p;
                Pw[(quad * 4 + r) * KS + s * 16 + l15] = (_Float16)p;
            }
        }
        __syncthreads();
        #pragma unroll
        for (int c = 0; c < 2; ++c) {
            const half8_t ap = *(const half8_t*)&Pw[l15 * KS + c * 32 + quad * 8];
            #pragma unroll
            for (int d = 0; d < 4; ++d) {
                const half8_t bv = *(const half8_t*)&Vt[(d * 16 + l15) * KS + c * 32 + quad * 8];
                ofr[d] = __builtin_amdgcn_mfma_f32_16x16x32_f16(ap, bv, ofr[d], 0, 0, 0);
            }
        }
    }
    #pragma unroll
    for (int r = 0; r < 4; ++r) {
        float v = lacc[r];
        v += __shfl_xor(v, 1, 64);
        v += __shfl_xor(v, 2, 64);
        v += __shfl_xor(v, 4, 64);
        v += __shfl_xor(v, 8, 64);
        lacc[r] = v;
    }
    #pragma unroll
    for (int r = 0; r < 4; ++r) {
        const float inv = 1.0f / lacc[r];
        float* orow = O + boff + (size_t)(qb + quad * 4 + r) * D_ + l15;
        #pragma unroll
        for (int d = 0; d < 4; ++d) orow[d * 16] = ofr[d][r] * inv;
    }
}

extern "C" void kernel_launch(void* const* d_in, const int* in_sizes, int n_in,
                              void* d_out, int out_size, void* d_ws, size_t ws_size,
                              hipStream_t stream) {
    const float* Q = (const float*)d_in[0];
    const float* K = (const float*)d_in[1];
    const float* V = (const float*)d_in[2];
    float* O = (float*)d_out;

    if (ws_size >= (size_t)8 * 1024 * 1024) {
        _Float16* K16F  = (_Float16*)d_ws;                             // 2 MB
        _Float16* VT16F = K16F + (size_t)1048576;                      // 2 MB

        void* args[] = { (void*)&Q, (void*)&K, (void*)&V,
                         (void*)&K16F, (void*)&VT16F, (void*)&O };
        hipError_t err = hipLaunchCooperativeKernel(
            (void*)attn_coop, dim3(512), dim3(512), args, 0, stream);
        if (err != hipSuccess) {
            // deterministic fallback: R14 two-launch path
            prepass_frag<<<1024, NT, 0, stream>>>(K, V, K16F, VT16F);
            attn_tlp<<<512, 512, 0, stream>>>(Q, K16F, VT16F, O);
        }
    } else {
        attn_mfma_f16<<<256, NT, 0, stream>>>(Q, K, V, O);
    }
}

// Round 16
// 84.915 us; speedup vs baseline: 2.8143x; 2.8143x over previous
//
#include <hip/hip_runtime.h>

// ScaledDotProductAttention B=8, L=2048, D=64, fp32 in/out.
//
// Two-launch scheme (ws >= 8 MB). R14 (best: 82.7us) + XCD-aligned prepass:
//  1) prepass_frag: writes K and V^T as MFMA fragments in the EXACT per-lane
//     order the attn waves consume. THIS ROUND: block index permuted so
//     b = blk&7 (was blk>>6) -- every prepass block for batch b runs on the
//     same XCD (blockIdx%8 heuristic) as ALL attn blocks of batch b, so the
//     512 KB frag set is written and read through one L2 (no cross-XCD L3
//     round trip). R15 proved the locality idea but grid.sync cost 130us;
//     this gets the locality for free.
//       K16F[((b*64+kt)*4 + s*2+c)*512 + lane*8]  (half8 = bk[s][c] of tile kt)
//       VT16F[((b*64+kt)*8 + d*2+ks)*256 + lane*4] (half4 = av[d][ks])
//  2) attn_tlp (R14 verbatim): grid 512 = 8 batch x 64 qblocks of 32 queries;
//     512 threads = 8 waves -> 4 waves/SIMD. Wave owns keys [wave*256,+256).
//     Zero LDS / zero cross-lane hot loop (R9-verified algebra):
//       - S^T = K*Q^T via mfma_f32_16x16x32_f16; lane holds
//         S^T[key=quad*4+r][q=qs*16+l15].
//       - p = exp2(s) (0.125*log2e folded into Q); packed half4 IS the
//         B-frag of mfma_f32_16x16x16f16 -> PV straight from registers.
//       - PV: O^T += VT16F half4 A-frags x P^T; float4-per-query store.
//     Epilogue: 2 rounds over 36 KB LDS; 8-wave (O,l) combine.
// Fallback: proven R3 kernel if ws too small.

#define B_ 8
#define L_ 2048
#define D_ 64
#define NT 256

typedef _Float16 half8_t __attribute__((ext_vector_type(8)));
typedef _Float16 half4_t __attribute__((ext_vector_type(4)));
typedef float f32x4 __attribute__((ext_vector_type(4)));

#define SCALE_LOG2E 0.1803368801111244f   // 0.125 * log2(e)

// ------------------------------------------------------------ prepass_frag --
// blocks 0..511: K fragments; 512..1023: V^T fragments.
// XCD-aligned: batch = blk&7 so writer XCD == reader XCD (attn: b=blockIdx&7).
__global__ __launch_bounds__(NT) void prepass_frag(
    const float* __restrict__ K, const float* __restrict__ V,
    _Float16* __restrict__ K16F, _Float16* __restrict__ VT16F)
{
    const int blk = blockIdx.x;
    const int t = threadIdx.x;
    if (blk < 512) {
        const int b  = blk & 7;
        const int kt = blk >> 3;
        const int p    = t >> 6;          // plane = s*2 + c
        const int lane = t & 63;
        const int quad = lane >> 4;
        const int l15  = lane & 15;
        const int s = p >> 1, c = p & 1;
        const int row = kt * 32 + s * 16 + l15;
        const float* kp = K + ((size_t)b * L_ + row) * D_ + c * 32 + quad * 8;
        const float4 f0 = *(const float4*)kp;
        const float4 f1 = *(const float4*)(kp + 4);
        half8_t w;
        w[0] = (_Float16)f0.x; w[1] = (_Float16)f0.y;
        w[2] = (_Float16)f0.z; w[3] = (_Float16)f0.w;
        w[4] = (_Float16)f1.x; w[5] = (_Float16)f1.y;
        w[6] = (_Float16)f1.z; w[7] = (_Float16)f1.w;
        *(half8_t*)&K16F[((size_t)(b * 64 + kt) * 4 + p) * 512 + lane * 8] = w;
    } else {
        const int vb = blk - 512;
        const int b  = vb & 7;
        const int kt = vb >> 3;
        #pragma unroll
        for (int i = 0; i < 2; ++i) {
            const int slot = i * NT + t;      // 512 slots = 8 planes x 64 lanes
            const int p    = slot >> 6;       // plane = d*2 + ks
            const int lane = slot & 63;
            const int quad = lane >> 4;
            const int l15  = lane & 15;
            const int d = p >> 1, ks = p & 1;
            const int row = kt * 32 + ks * 16 + quad * 4;
            const int col = d * 16 + l15;
            const float* vp = V + ((size_t)b * L_ + row) * D_ + col;
            half4_t a;
            a[0] = (_Float16)vp[0];
            a[1] = (_Float16)vp[D_];
            a[2] = (_Float16)vp[2 * D_];
            a[3] = (_Float16)vp[3 * D_];
            *(half4_t*)&VT16F[((size_t)(b * 64 + kt) * 8 + p) * 256 + lane * 4] = a;
        }
    }
}

// -------------------------------------------------------------- main body --

// Load K B-frags of tile KT: one fully-coalesced half8/lane stream per plane.
#define LOADK(KT, BK)                                                           \
    {                                                                           \
        _Pragma("unroll") for (int s = 0; s < 2; ++s)                           \
        _Pragma("unroll") for (int c = 0; c < 2; ++c)                           \
            BK[s][c] = *(const half8_t*)&KbF[((size_t)(KT) * 4 + s * 2 + c) * 512 + lane * 8]; \
    }

// Process tile KT using pre-loaded K frags BK.
#define PROC(KT, BK)                                                            \
    {                                                                           \
        half4_t av[4][2];                                                       \
        _Pragma("unroll") for (int d = 0; d < 4; ++d)                           \
        _Pragma("unroll") for (int ks = 0; ks < 2; ++ks)                        \
            av[d][ks] = *(const half4_t*)&VbF[((size_t)(KT) * 8 + d * 2 + ks) * 256 + lane * 4]; \
        f32x4 sc[2][2];                                                         \
        _Pragma("unroll") for (int ks = 0; ks < 2; ++ks)                        \
        _Pragma("unroll") for (int qs = 0; qs < 2; ++qs) {                      \
            f32x4 acc = (f32x4){0.f, 0.f, 0.f, 0.f};                            \
            acc = __builtin_amdgcn_mfma_f32_16x16x32_f16(BK[ks][0], bq[qs][0], acc, 0, 0, 0); \
            acc = __builtin_amdgcn_mfma_f32_16x16x32_f16(BK[ks][1], bq[qs][1], acc, 0, 0, 0); \
            sc[ks][qs] = acc;                                                   \
        }                                                                       \
        half4_t pb[2][2];                                                       \
        _Pragma("unroll") for (int ks = 0; ks < 2; ++ks)                        \
        _Pragma("unroll") for (int qs = 0; qs < 2; ++qs) {                      \
            const float p0 = __builtin_exp2f(sc[ks][qs][0]);                    \
            const float p1 = __builtin_exp2f(sc[ks][qs][1]);                    \
            const float p2 = __builtin_exp2f(sc[ks][qs][2]);                    \
            const float p3 = __builtin_exp2f(sc[ks][qs][3]);                    \
            lacc[qs] += (p0 + p1) + (p2 + p3);                                  \
            half4_t pv;                                                         \
            pv[0] = (_Float16)p0; pv[1] = (_Float16)p1;                         \
            pv[2] = (_Float16)p2; pv[3] = (_Float16)p3;                         \
            pb[ks][qs] = pv;                                                    \
        }                                                                       \
        _Pragma("unroll") for (int qs = 0; qs < 2; ++qs)                        \
        _Pragma("unroll") for (int d = 0; d < 4; ++d)                           \
        _Pragma("unroll") for (int ks = 0; ks < 2; ++ks)                        \
            ofr[qs][d] = __builtin_amdgcn_mfma_f32_16x16x16f16(av[d][ks], pb[ks][qs], ofr[qs][d], 0, 0, 0); \
    }

__global__ __launch_bounds__(512, 4) void attn_tlp(
    const float* __restrict__ Q,
    const _Float16* __restrict__ K16F,
    const _Float16* __restrict__ VT16F,
    float* __restrict__ O)
{
    __shared__ float Ored[512 * 17];                     // 34816 B (epilogue only)
    __shared__ float Lred[256];                          // 1 KB

    const int t    = threadIdx.x;
    const int wave = t >> 6;                   // 0..7 (key-range owner)
    const int lane = t & 63;
    const int quad = lane >> 4;
    const int l15  = lane & 15;

    const int b   = blockIdx.x & 7;            // batch <-> XCD affinity
    const int qbi = blockIdx.x >> 3;           // query block 0..63
    const int qb  = qbi * 32;
    const int kt0 = wave * 8;                  // wave's 8 tiles (256 keys)

    const _Float16* KbF = K16F + (size_t)b * 64 * 4 * 512;
    const _Float16* VbF = VT16F + (size_t)b * 64 * 8 * 256;

    // ---- Q B-frags from fp32, pre-scaled by 0.125*log2(e) ----
    half8_t bq[2][2];
    #pragma unroll
    for (int qs = 0; qs < 2; ++qs) {
        const float* qp = Q + ((size_t)b * L_ + qb + qs * 16 + l15) * D_ + quad * 8;
        #pragma unroll
        for (int c = 0; c < 2; ++c) {
            const float4 f0 = *(const float4*)(qp + c * 32);
            const float4 f1 = *(const float4*)(qp + c * 32 + 4);
            bq[qs][c][0] = (_Float16)(f0.x * SCALE_LOG2E);
            bq[qs][c][1] = (_Float16)(f0.y * SCALE_LOG2E);
            bq[qs][c][2] = (_Float16)(f0.z * SCALE_LOG2E);
            bq[qs][c][3] = (_Float16)(f0.w * SCALE_LOG2E);
            bq[qs][c][4] = (_Float16)(f1.x * SCALE_LOG2E);
            bq[qs][c][5] = (_Float16)(f1.y * SCALE_LOG2E);
            bq[qs][c][6] = (_Float16)(f1.z * SCALE_LOG2E);
            bq[qs][c][7] = (_Float16)(f1.w * SCALE_LOG2E);
        }
    }

    f32x4 ofr[2][4];
    #pragma unroll
    for (int qs = 0; qs < 2; ++qs)
        #pragma unroll
        for (int d = 0; d < 4; ++d)
            ofr[qs][d] = (f32x4){0.f, 0.f, 0.f, 0.f};
    float lacc[2] = {0.f, 0.f};

    // ---- hot loop: 8 tiles of 32 keys, K frags double-buffered ----
    half8_t bkA[2][2], bkB[2][2];
    LOADK(kt0, bkA);
    for (int it = 0; it < 4; ++it) {
        const int kta = kt0 + it * 2;
        LOADK(kta + 1, bkB);
        PROC(kta, bkA);
        // final prefetch overruns the wave's tile range; stays inside the ws
        // mapping (K16F is followed by VT16F) and is never consumed.
        LOADK(kta + 2, bkA);
        PROC(kta + 1, bkB);
    }

    // ---- l: reduce over quads (each lane holds 4 keys of query qs*16+l15) --
    #pragma unroll
    for (int qs = 0; qs < 2; ++qs) {
        float v = lacc[qs];
        v += __shfl_xor(v, 16, 64);
        v += __shfl_xor(v, 32, 64);
        lacc[qs] = v;
    }
    if (quad == 0) {
        Lred[wave * 32 + l15] = lacc[0];
        Lred[wave * 32 + 16 + l15] = lacc[1];
    }

    // ---- cross-wave combine: 2 rounds (one qs each) over shared buffer ----
    #pragma unroll
    for (int qs = 0; qs < 2; ++qs) {
        __syncthreads();   // previous round's reads (and Lred writes) done
        #pragma unroll
        for (int d = 0; d < 4; ++d)
            #pragma unroll
            for (int r = 0; r < 4; ++r)
                Ored[(wave * 64 + lane) * 17 + d * 4 + r] = ofr[qs][d][r];
        __syncthreads();
        if (wave < 4) {
            float lt = 0.f;
            #pragma unroll
            for (int w2 = 0; w2 < 8; ++w2)
                lt += Lred[w2 * 32 + qs * 16 + l15];
            const float inv = 1.0f / lt;
            f32x4 osum = (f32x4){0.f, 0.f, 0.f, 0.f};
            #pragma unroll
            for (int w2 = 0; w2 < 8; ++w2) {
                const float* src = &Ored[(w2 * 64 + lane) * 17 + wave * 4];
                osum[0] += src[0]; osum[1] += src[1];
                osum[2] += src[2]; osum[3] += src[3];
            }
            float4 outv;
            outv.x = osum[0] * inv; outv.y = osum[1] * inv;
            outv.z = osum[2] * inv; outv.w = osum[3] * inv;
            // query = qb + qs*16 + l15 ; dims = wave*16 + quad*4 .. +4
            *(float4*)&O[((size_t)b * L_ + qb + qs * 16 + l15) * D_ + wave * 16 + quad * 4] = outv;
        }
    }
}

// ------------------------------------------------- fallback (R3, no ws) --
#define KS 72
__global__ __launch_bounds__(NT) void attn_mfma_f16(
    const float* __restrict__ Q, const float* __restrict__ K,
    const float* __restrict__ V, float* __restrict__ O)
{
    __shared__ __align__(16) _Float16 Kt[64 * KS];
    __shared__ __align__(16) _Float16 Vt[D_ * KS];
    __shared__ __align__(16) _Float16 Pt[4][16 * KS];

    const int t = threadIdx.x;
    const int wave = t >> 6, lane = t & 63, quad = lane >> 4, l15 = lane & 15;
    const int bpb = L_ / 64;
    const int b = blockIdx.x / bpb;
    const int qb = (blockIdx.x % bpb) * 64 + wave * 16;
    const size_t boff = (size_t)b * L_ * D_;

    half8_t aq[2];
    {
        const float* qp = Q + boff + (size_t)(qb + l15) * D_ + quad * 8;
        #pragma unroll
        for (int c = 0; c < 2; ++c) {
            const float4* p4 = (const float4*)(qp + c * 32);
            const float4 f0 = p4[0], f1 = p4[1];
            aq[c][0] = (_Float16)f0.x; aq[c][1] = (_Float16)f0.y;
            aq[c][2] = (_Float16)f0.z; aq[c][3] = (_Float16)f0.w;
            aq[c][4] = (_Float16)f1.x; aq[c][5] = (_Float16)f1.y;
            aq[c][6] = (_Float16)f1.z; aq[c][7] = (_Float16)f1.w;
        }
    }
    f32x4 ofr[4];
    #pragma unroll
    for (int d = 0; d < 4; ++d) ofr[d] = (f32x4){0.f, 0.f, 0.f, 0.f};
    float lacc[4] = {0.f, 0.f, 0.f, 0.f};
    const int skey = t & 63, sdg = t >> 6;
    _Float16* Pw = &Pt[wave][0];

    for (int kt = 0; kt < L_ / 64; ++kt) {
        __syncthreads();
        {
            const float4* kg4 = (const float4*)(K + boff + (size_t)(kt * 64 + skey) * D_ + sdg * 16);
            const float4 f0 = kg4[0], f1 = kg4[1], f2 = kg4[2], f3 = kg4[3];
            half8_t w0, w1;
            w0[0] = (_Float16)f0.x; w0[1] = (_Float16)f0.y;
            w0[2] = (_Float16)f0.z; w0[3] = (_Float16)f0.w;
            w0[4] = (_Float16)f1.x; w0[5] = (_Float16)f1.y;
            w0[6] = (_Float16)f1.z; w0[7] = (_Float16)f1.w;
            w1[0] = (_Float16)f2.x; w1[1] = (_Float16)f2.y;
            w1[2] = (_Float16)f2.z; w1[3] = (_Float16)f2.w;
            w1[4] = (_Float16)f3.x; w1[5] = (_Float16)f3.y;
            w1[6] = (_Float16)f3.z; w1[7] = (_Float16)f3.w;
            *(half8_t*)&Kt[skey * KS + sdg * 16] = w0;
            *(half8_t*)&Kt[skey * KS + sdg * 16 + 8] = w1;
        }
        {
            const float4* vg4 = (const float4*)(V + boff + (size_t)(kt * 64 + skey) * D_ + sdg * 16);
            #pragma unroll
            for (int i = 0; i < 4; ++i) {
                const float4 f = vg4[i];
                const int d0 = sdg * 16 + i * 4;
                Vt[(d0 + 0) * KS + skey] = (_Float16)f.x;
                Vt[(d0 + 1) * KS + skey] = (_Float16)f.y;
                Vt[(d0 + 2) * KS + skey] = (_Float16)f.z;
                Vt[(d0 + 3) * KS + skey] = (_Float16)f.w;
            }
        }
        __syncthreads();
        #pragma unroll
        for (int s = 0; s < 4; ++s) {
            const half8_t bk0 = *(const half8_t*)&Kt[(s * 16 + l15) * KS + quad * 8];
            const half8_t bk1 = *(const half8_t*)&Kt[(s * 16 + l15) * KS + 32 + quad * 8];
            f32x4 sc = (f32x4){0.f, 0.f, 0.f, 0.f};
            sc = __builtin_amdgcn_mfma_f32_16x16x32_f16(aq[0], bk0, sc, 0, 0, 0);
            sc = __builtin_amdgcn_mfma_f32_16x16x32_f16(aq[1], bk1, sc, 0, 0, 0);
            #pragma unroll
            for (int r = 0; r < 4; ++r) {
                const float p = __expf(sc[r] * 0.125f);
                lacc[r] += p;
                Pw[(quad * 4 + r) * KS + s * 16 + l15] = (_Float16)p;
            }
        }
        __syncthreads();
        #pragma unroll
        for (int c = 0; c < 2; ++c) {
            const half8_t ap = *(const half8_t*)&Pw[l15 * KS + c * 32 + quad * 8];
            #pragma unroll
            for (int d = 0; d < 4; ++d) {
                const half8_t bv = *(const half8_t*)&Vt[(d * 16 + l15) * KS + c * 32 + quad * 8];
                ofr[d] = __builtin_amdgcn_mfma_f32_16x16x32_f16(ap, bv, ofr[d], 0, 0, 0);
            }
        }
    }
    #pragma unroll
    for (int r = 0; r < 4; ++r) {
        float v = lacc[r];
        v += __shfl_xor(v, 1, 64);
        v += __shfl_xor(v, 2, 64);
        v += __shfl_xor(v, 4, 64);
        v += __shfl_xor(v, 8, 64);
        lacc[r] = v;
    }
    #pragma unroll
    for (int r = 0; r < 4; ++r) {
        const float inv = 1.0f / lacc[r];
        float* orow = O + boff + (size_t)(qb + quad * 4 + r) * D_ + l15;
        #pragma unroll
        for (int d = 0; d < 4; ++d) orow[d * 16] = ofr[d][r] * inv;
    }
}

extern "C" void kernel_launch(void* const* d_in, const int* in_sizes, int n_in,
                              void* d_out, int out_size, void* d_ws, size_t ws_size,
                              hipStream_t stream) {
    const float* Q = (const float*)d_in[0];
    const float* K = (const float*)d_in[1];
    const float* V = (const float*)d_in[2];
    float* O = (float*)d_out;

    if (ws_size >= (size_t)8 * 1024 * 1024) {
        _Float16* K16F  = (_Float16*)d_ws;                             // 2 MB
        _Float16* VT16F = K16F + (size_t)1048576;                      // 2 MB
        prepass_frag<<<1024, NT, 0, stream>>>(K, V, K16F, VT16F);
        attn_tlp<<<512, 512, 0, stream>>>(Q, K16F, VT16F, O);
    } else {
        attn_mfma_f16<<<256, NT, 0, stream>>>(Q, K, V, O);
    }
}

// Round 17
// 83.368 us; speedup vs baseline: 2.8665x; 1.0186x over previous
//
#include <hip/hip_runtime.h>

// ScaledDotProductAttention B=8, L=2048, D=64, fp32 in/out.
//
// Two-launch scheme (ws >= 8 MB). R14 attn (best: 82.7us) + MERGED prepass:
//  1) prepass_frag: 512 blocks (was 1024) -- block (b,kt) writes BOTH the K
//     fragments (1 half8/thread) and V^T fragments (2 half4/thread) of its
//     32-key tile. Halves dispatch count / scheduling tail. R14's indexing
//     (b = blk>>6) kept; R16's XCD-align variant measured -2.2us -> reverted.
//     Fragment-major layout (R13's verified ~7us win -- kills the
//     row-per-lane VMEM scatter in the hot loop):
//       K16F[((b*64+kt)*4 + s*2+c)*512 + lane*8]  (half8 = bk[s][c] of tile kt)
//       VT16F[((b*64+kt)*8 + d*2+ks)*256 + lane*4] (half4 = av[d][ks])
//  2) attn_tlp (R14 verbatim): grid 512 = 8 batch x 64 qblocks of 32 queries;
//     512 threads = 8 waves -> 4 waves/SIMD. Wave owns keys [wave*256,+256).
//     Zero LDS / zero cross-lane hot loop (R9-verified algebra):
//       - S^T = K*Q^T via mfma_f32_16x16x32_f16; lane holds
//         S^T[key=quad*4+r][q=qs*16+l15].
//       - p = exp2(s) (0.125*log2e folded into Q); packed half4 IS the
//         B-frag of mfma_f32_16x16x16f16 -> PV straight from registers.
//       - PV: O^T += VT16F half4 A-frags x P^T; float4-per-query store.
//     Epilogue: 2 rounds over 36 KB LDS; 8-wave (O,l) combine.
// Fallback: proven R3 kernel if ws too small.

#define B_ 8
#define L_ 2048
#define D_ 64
#define NT 256

typedef _Float16 half8_t __attribute__((ext_vector_type(8)));
typedef _Float16 half4_t __attribute__((ext_vector_type(4)));
typedef float f32x4 __attribute__((ext_vector_type(4)));

#define SCALE_LOG2E 0.1803368801111244f   // 0.125 * log2(e)

// ------------------------------------------------------------ prepass_frag --
// 512 blocks: block (b,kt) writes K frags (planes 0..3, one per wave-slot
// group) and V^T frags (planes 0..7, two slots per thread) of tile kt.
__global__ __launch_bounds__(NT) void prepass_frag(
    const float* __restrict__ K, const float* __restrict__ V,
    _Float16* __restrict__ K16F, _Float16* __restrict__ VT16F)
{
    const int blk = blockIdx.x;
    const int t = threadIdx.x;
    const int b  = blk >> 6;
    const int kt = blk & 63;

    // ---- K fragments: 4 planes x 64 lanes = 256 slots (one per thread) ----
    {
        const int p    = t >> 6;          // plane = s*2 + c
        const int lane = t & 63;
        const int quad = lane >> 4;
        const int l15  = lane & 15;
        const int s = p >> 1, c = p & 1;
        const int row = kt * 32 + s * 16 + l15;
        const float* kp = K + ((size_t)b * L_ + row) * D_ + c * 32 + quad * 8;
        const float4 f0 = *(const float4*)kp;
        const float4 f1 = *(const float4*)(kp + 4);
        half8_t w;
        w[0] = (_Float16)f0.x; w[1] = (_Float16)f0.y;
        w[2] = (_Float16)f0.z; w[3] = (_Float16)f0.w;
        w[4] = (_Float16)f1.x; w[5] = (_Float16)f1.y;
        w[6] = (_Float16)f1.z; w[7] = (_Float16)f1.w;
        *(half8_t*)&K16F[((size_t)(b * 64 + kt) * 4 + p) * 512 + lane * 8] = w;
    }

    // ---- V^T fragments: 8 planes x 64 lanes = 512 slots (two per thread) ----
    #pragma unroll
    for (int i = 0; i < 2; ++i) {
        const int slot = i * NT + t;
        const int p    = slot >> 6;       // plane = d*2 + ks
        const int lane = slot & 63;
        const int quad = lane >> 4;
        const int l15  = lane & 15;
        const int d = p >> 1, ks = p & 1;
        const int row = kt * 32 + ks * 16 + quad * 4;
        const int col = d * 16 + l15;
        const float* vp = V + ((size_t)b * L_ + row) * D_ + col;
        half4_t a;
        a[0] = (_Float16)vp[0];
        a[1] = (_Float16)vp[D_];
        a[2] = (_Float16)vp[2 * D_];
        a[3] = (_Float16)vp[3 * D_];
        *(half4_t*)&VT16F[((size_t)(b * 64 + kt) * 8 + p) * 256 + lane * 4] = a;
    }
}

// -------------------------------------------------------------- main body --

// Load K B-frags of tile KT: one fully-coalesced half8/lane stream per plane.
#define LOADK(KT, BK)                                                           \
    {                                                                           \
        _Pragma("unroll") for (int s = 0; s < 2; ++s)                           \
        _Pragma("unroll") for (int c = 0; c < 2; ++c)                           \
            BK[s][c] = *(const half8_t*)&KbF[((size_t)(KT) * 4 + s * 2 + c) * 512 + lane * 8]; \
    }

// Process tile KT using pre-loaded K frags BK.
#define PROC(KT, BK)                                                            \
    {                                                                           \
        half4_t av[4][2];                                                       \
        _Pragma("unroll") for (int d = 0; d < 4; ++d)                           \
        _Pragma("unroll") for (int ks = 0; ks < 2; ++ks)                        \
            av[d][ks] = *(const half4_t*)&VbF[((size_t)(KT) * 8 + d * 2 + ks) * 256 + lane * 4]; \
        f32x4 sc[2][2];                                                         \
        _Pragma("unroll") for (int ks = 0; ks < 2; ++ks)                        \
        _Pragma("unroll") for (int qs = 0; qs < 2; ++qs) {                      \
            f32x4 acc = (f32x4){0.f, 0.f, 0.f, 0.f};                            \
            acc = __builtin_amdgcn_mfma_f32_16x16x32_f16(BK[ks][0], bq[qs][0], acc, 0, 0, 0); \
            acc = __builtin_amdgcn_mfma_f32_16x16x32_f16(BK[ks][1], bq[qs][1], acc, 0, 0, 0); \
            sc[ks][qs] = acc;                                                   \
        }                                                                       \
        half4_t pb[2][2];                                                       \
        _Pragma("unroll") for (int ks = 0; ks < 2; ++ks)                        \
        _Pragma("unroll") for (int qs = 0; qs < 2; ++qs) {                      \
            const float p0 = __builtin_exp2f(sc[ks][qs][0]);                    \
            const float p1 = __builtin_exp2f(sc[ks][qs][1]);                    \
            const float p2 = __builtin_exp2f(sc[ks][qs][2]);                    \
            const float p3 = __builtin_exp2f(sc[ks][qs][3]);                    \
            lacc[qs] += (p0 + p1) + (p2 + p3);                                  \
            half4_t pv;                                                         \
            pv[0] = (_Float16)p0; pv[1] = (_Float16)p1;                         \
            pv[2] = (_Float16)p2; pv[3] = (_Float16)p3;                         \
            pb[ks][qs] = pv;                                                    \
        }                                                                       \
        _Pragma("unroll") for (int qs = 0; qs < 2; ++qs)                        \
        _Pragma("unroll") for (int d = 0; d < 4; ++d)                           \
        _Pragma("unroll") for (int ks = 0; ks < 2; ++ks)                        \
            ofr[qs][d] = __builtin_amdgcn_mfma_f32_16x16x16f16(av[d][ks], pb[ks][qs], ofr[qs][d], 0, 0, 0); \
    }

__global__ __launch_bounds__(512, 4) void attn_tlp(
    const float* __restrict__ Q,
    const _Float16* __restrict__ K16F,
    const _Float16* __restrict__ VT16F,
    float* __restrict__ O)
{
    __shared__ float Ored[512 * 17];                     // 34816 B (epilogue only)
    __shared__ float Lred[256];                          // 1 KB

    const int t    = threadIdx.x;
    const int wave = t >> 6;                   // 0..7 (key-range owner)
    const int lane = t & 63;
    const int quad = lane >> 4;
    const int l15  = lane & 15;

    const int b   = blockIdx.x & 7;            // batch <-> XCD affinity
    const int qbi = blockIdx.x >> 3;           // query block 0..63
    const int qb  = qbi * 32;
    const int kt0 = wave * 8;                  // wave's 8 tiles (256 keys)

    const _Float16* KbF = K16F + (size_t)b * 64 * 4 * 512;
    const _Float16* VbF = VT16F + (size_t)b * 64 * 8 * 256;

    // ---- Q B-frags from fp32, pre-scaled by 0.125*log2(e) ----
    half8_t bq[2][2];
    #pragma unroll
    for (int qs = 0; qs < 2; ++qs) {
        const float* qp = Q + ((size_t)b * L_ + qb + qs * 16 + l15) * D_ + quad * 8;
        #pragma unroll
        for (int c = 0; c < 2; ++c) {
            const float4 f0 = *(const float4*)(qp + c * 32);
            const float4 f1 = *(const float4*)(qp + c * 32 + 4);
            bq[qs][c][0] = (_Float16)(f0.x * SCALE_LOG2E);
            bq[qs][c][1] = (_Float16)(f0.y * SCALE_LOG2E);
            bq[qs][c][2] = (_Float16)(f0.z * SCALE_LOG2E);
            bq[qs][c][3] = (_Float16)(f0.w * SCALE_LOG2E);
            bq[qs][c][4] = (_Float16)(f1.x * SCALE_LOG2E);
            bq[qs][c][5] = (_Float16)(f1.y * SCALE_LOG2E);
            bq[qs][c][6] = (_Float16)(f1.z * SCALE_LOG2E);
            bq[qs][c][7] = (_Float16)(f1.w * SCALE_LOG2E);
        }
    }

    f32x4 ofr[2][4];
    #pragma unroll
    for (int qs = 0; qs < 2; ++qs)
        #pragma unroll
        for (int d = 0; d < 4; ++d)
            ofr[qs][d] = (f32x4){0.f, 0.f, 0.f, 0.f};
    float lacc[2] = {0.f, 0.f};

    // ---- hot loop: 8 tiles of 32 keys, K frags double-buffered ----
    half8_t bkA[2][2], bkB[2][2];
    LOADK(kt0, bkA);
    for (int it = 0; it < 4; ++it) {
        const int kta = kt0 + it * 2;
        LOADK(kta + 1, bkB);
        PROC(kta, bkA);
        // final prefetch overruns the wave's tile range; stays inside the ws
        // mapping (K16F is followed by VT16F) and is never consumed.
        LOADK(kta + 2, bkA);
        PROC(kta + 1, bkB);
    }

    // ---- l: reduce over quads (each lane holds 4 keys of query qs*16+l15) --
    #pragma unroll
    for (int qs = 0; qs < 2; ++qs) {
        float v = lacc[qs];
        v += __shfl_xor(v, 16, 64);
        v += __shfl_xor(v, 32, 64);
        lacc[qs] = v;
    }
    if (quad == 0) {
        Lred[wave * 32 + l15] = lacc[0];
        Lred[wave * 32 + 16 + l15] = lacc[1];
    }

    // ---- cross-wave combine: 2 rounds (one qs each) over shared buffer ----
    #pragma unroll
    for (int qs = 0; qs < 2; ++qs) {
        __syncthreads();   // previous round's reads (and Lred writes) done
        #pragma unroll
        for (int d = 0; d < 4; ++d)
            #pragma unroll
            for (int r = 0; r < 4; ++r)
                Ored[(wave * 64 + lane) * 17 + d * 4 + r] = ofr[qs][d][r];
        __syncthreads();
        if (wave < 4) {
            float lt = 0.f;
            #pragma unroll
            for (int w2 = 0; w2 < 8; ++w2)
                lt += Lred[w2 * 32 + qs * 16 + l15];
            const float inv = 1.0f / lt;
            f32x4 osum = (f32x4){0.f, 0.f, 0.f, 0.f};
            #pragma unroll
            for (int w2 = 0; w2 < 8; ++w2) {
                const float* src = &Ored[(w2 * 64 + lane) * 17 + wave * 4];
                osum[0] += src[0]; osum[1] += src[1];
                osum[2] += src[2]; osum[3] += src[3];
            }
            float4 outv;
            outv.x = osum[0] * inv; outv.y = osum[1] * inv;
            outv.z = osum[2] * inv; outv.w = osum[3] * inv;
            // query = qb + qs*16 + l15 ; dims = wave*16 + quad*4 .. +4
            *(float4*)&O[((size_t)b * L_ + qb + qs * 16 + l15) * D_ + wave * 16 + quad * 4] = outv;
        }
    }
}

// ------------------------------------------------- fallback (R3, no ws) --
#define KS 72
__global__ __launch_bounds__(NT) void attn_mfma_f16(
    const float* __restrict__ Q, const float* __restrict__ K,
    const float* __restrict__ V, float* __restrict__ O)
{
    __shared__ __align__(16) _Float16 Kt[64 * KS];
    __shared__ __align__(16) _Float16 Vt[D_ * KS];
    __shared__ __align__(16) _Float16 Pt[4][16 * KS];

    const int t = threadIdx.x;
    const int wave = t >> 6, lane = t & 63, quad = lane >> 4, l15 = lane & 15;
    const int bpb = L_ / 64;
    const int b = blockIdx.x / bpb;
    const int qb = (blockIdx.x % bpb) * 64 + wave * 16;
    const size_t boff = (size_t)b * L_ * D_;

    half8_t aq[2];
    {
        const float* qp = Q + boff + (size_t)(qb + l15) * D_ + quad * 8;
        #pragma unroll
        for (int c = 0; c < 2; ++c) {
            const float4* p4 = (const float4*)(qp + c * 32);
            const float4 f0 = p4[0], f1 = p4[1];
            aq[c][0] = (_Float16)f0.x; aq[c][1] = (_Float16)f0.y;
            aq[c][2] = (_Float16)f0.z; aq[c][3] = (_Float16)f0.w;
            aq[c][4] = (_Float16)f1.x; aq[c][5] = (_Float16)f1.y;
            aq[c][6] = (_Float16)f1.z; aq[c][7] = (_Float16)f1.w;
        }
    }
    f32x4 ofr[4];
    #pragma unroll
    for (int d = 0; d < 4; ++d) ofr[d] = (f32x4){0.f, 0.f, 0.f, 0.f};
    float lacc[4] = {0.f, 0.f, 0.f, 0.f};
    const int skey = t & 63, sdg = t >> 6;
    _Float16* Pw = &Pt[wave][0];

    for (int kt = 0; kt < L_ / 64; ++kt) {
        __syncthreads();
        {
            const float4* kg4 = (const float4*)(K + boff + (size_t)(kt * 64 + skey) * D_ + sdg * 16);
            const float4 f0 = kg4[0], f1 = kg4[1], f2 = kg4[2], f3 = kg4[3];
            half8_t w0, w1;
            w0[0] = (_Float16)f0.x; w0[1] = (_Float16)f0.y;
            w0[2] = (_Float16)f0.z; w0[3] = (_Float16)f0.w;
            w0[4] = (_Float16)f1.x; w0[5] = (_Float16)f1.y;
            w0[6] = (_Float16)f1.z; w0[7] = (_Float16)f1.w;
            w1[0] = (_Float16)f2.x; w1[1] = (_Float16)f2.y;
            w1[2] = (_Float16)f2.z; w1[3] = (_Float16)f2.w;
            w1[4] = (_Float16)f3.x; w1[5] = (_Float16)f3.y;
            w1[6] = (_Float16)f3.z; w1[7] = (_Float16)f3.w;
            *(half8_t*)&Kt[skey * KS + sdg * 16] = w0;
            *(half8_t*)&Kt[skey * KS + sdg * 16 + 8] = w1;
        }
        {
            const float4* vg4 = (const float4*)(V + boff + (size_t)(kt * 64 + skey) * D_ + sdg * 16);
            #pragma unroll
            for (int i = 0; i < 4; ++i) {
                const float4 f = vg4[i];
                const int d0 = sdg * 16 + i * 4;
                Vt[(d0 + 0) * KS + skey] = (_Float16)f.x;
                Vt[(d0 + 1) * KS + skey] = (_Float16)f.y;
                Vt[(d0 + 2) * KS + skey] = (_Float16)f.z;
                Vt[(d0 + 3) * KS + skey] = (_Float16)f.w;
            }
        }
        __syncthreads();
        #pragma unroll
        for (int s = 0; s < 4; ++s) {
            const half8_t bk0 = *(const half8_t*)&Kt[(s * 16 + l15) * KS + quad * 8];
            const half8_t bk1 = *(const half8_t*)&Kt[(s * 16 + l15) * KS + 32 + quad * 8];
            f32x4 sc = (f32x4){0.f, 0.f, 0.f, 0.f};
            sc = __builtin_amdgcn_mfma_f32_16x16x32_f16(aq[0], bk0, sc, 0, 0, 0);
            sc = __builtin_amdgcn_mfma_f32_16x16x32_f16(aq[1], bk1, sc, 0, 0, 0);
            #pragma unroll
            for (int r = 0; r < 4; ++r) {
                const float p = __expf(sc[r] * 0.125f);
                lacc[r] += p;
                Pw[(quad * 4 + r) * KS + s * 16 + l15] = (_Float16)p;
            }
        }
        __syncthreads();
        #pragma unroll
        for (int c = 0; c < 2; ++c) {
            const half8_t ap = *(const half8_t*)&Pw[l15 * KS + c * 32 + quad * 8];
            #pragma unroll
            for (int d = 0; d < 4; ++d) {
                const half8_t bv = *(const half8_t*)&Vt[(d * 16 + l15) * KS + c * 32 + quad * 8];
                ofr[d] = __builtin_amdgcn_mfma_f32_16x16x32_f16(ap, bv, ofr[d], 0, 0, 0);
            }
        }
    }
    #pragma unroll
    for (int r = 0; r < 4; ++r) {
        float v = lacc[r];
        v += __shfl_xor(v, 1, 64);
        v += __shfl_xor(v, 2, 64);
        v += __shfl_xor(v, 4, 64);
        v += __shfl_xor(v, 8, 64);
        lacc[r] = v;
    }
    #pragma unroll
    for (int r = 0; r < 4; ++r) {
        const float inv = 1.0f / lacc[r];
        float* orow = O + boff + (size_t)(qb + quad * 4 + r) * D_ + l15;
        #pragma unroll
        for (int d = 0; d < 4; ++d) orow[d * 16] = ofr[d][r] * inv;
    }
}

extern "C" void kernel_launch(void* const* d_in, const int* in_sizes, int n_in,
                              void* d_out, int out_size, void* d_ws, size_t ws_size,
                              hipStream_t stream) {
    const float* Q = (const float*)d_in[0];
    const float* K = (const float*)d_in[1];
    const float* V = (const float*)d_in[2];
    float* O = (float*)d_out;

    if (ws_size >= (size_t)8 * 1024 * 1024) {
        _Float16* K16F  = (_Float16*)d_ws;                             // 2 MB
        _Float16* VT16F = K16F + (size_t)1048576;                      // 2 MB
        prepass_frag<<<512, NT, 0, stream>>>(K, V, K16F, VT16F);
        attn_tlp<<<512, 512, 0, stream>>>(Q, K16F, VT16F, O);
    } else {
        attn_mfma_f16<<<256, NT, 0, stream>>>(Q, K, V, O);
    }
}